// Round 1
// baseline (1230.349 us; speedup 1.0000x reference)
//
#include <hip/hip_runtime.h>
#include <hip/hip_bf16.h>
#include <cstdint>

#define LATN 16
#define LONGN 12
#define PP 192          // LAT*LONG positions per n
#define CIN 128
#define CMID 128
#define EPSV 1e-5f

// ---------------- counting sort of scatter records by destination n ----------------

__global__ void count_kernel(const int* __restrict__ pidx, int* __restrict__ counts, int E) {
    int e = blockIdx.x * 256 + threadIdx.x;
    if (e >= E) return;
#pragma unroll
    for (int i = 0; i < 4; i++) {
        int v = pidx[i * E + e];
        int n = v / PP;
        atomicAdd(&counts[n], 1);
    }
}

// single block, 1024 threads, N <= 4096. counts may alias cur.
__global__ void scan_kernel(const int* __restrict__ counts, int* __restrict__ start,
                            int* __restrict__ cur, int N) {
    __shared__ int sdata[1024];
    int tid = threadIdx.x;
    int c[4];
    int s = 0;
#pragma unroll
    for (int j = 0; j < 4; j++) {
        int idx = tid * 4 + j;
        c[j] = (idx < N) ? counts[idx] : 0;
        s += c[j];
    }
    sdata[tid] = s;
    __syncthreads();
    for (int off = 1; off < 1024; off <<= 1) {
        int t = (tid >= off) ? sdata[tid - off] : 0;
        __syncthreads();
        sdata[tid] += t;
        __syncthreads();
    }
    int excl = sdata[tid] - s;
#pragma unroll
    for (int j = 0; j < 4; j++) {
        int idx = tid * 4 + j;
        if (idx < N) { start[idx] = excl; cur[idx] = excl; }
        excl += c[j];
    }
    if (tid == 1023) start[N] = sdata[1023];
}

// emit bucketed records: recA = src | (p<<18), recB = delta
__global__ void record_kernel(const int* __restrict__ pidx, const int* __restrict__ src_idx,
                              const float* __restrict__ delta, int* __restrict__ cur,
                              uint32_t* __restrict__ recA, float* __restrict__ recB, int E) {
    int e = blockIdx.x * 256 + threadIdx.x;
    if (e >= E) return;
    int src = src_idx[e];
#pragma unroll
    for (int i = 0; i < 4; i++) {
        int v = pidx[i * E + e];
        int n = v / PP;
        int p = v - n * PP;
        int pos = atomicAdd(&cur[n], 1);
        recA[pos] = (uint32_t)src | ((uint32_t)p << 18);
        recB[pos] = delta[i * E + e];
    }
}

// transpose conv weights [o][i][k] -> [i][k][o] for lane-coalesced loads
__global__ void wt_kernel(const float* __restrict__ w, float* __restrict__ wt, int total) {
    int id = blockIdx.x * 256 + threadIdx.x;
    if (id >= total) return;
    int o = id / (CIN * LONGN);
    int rem = id - o * (CIN * LONGN);
    int i = rem / LONGN;
    int k = rem - i * LONGN;
    wt[(i * LONGN + k) * CMID + o] = w[id];
}

// ---------------- fused: scatter->LDS tile, conv, silu, pool, groupnorm ----------------

__global__ __launch_bounds__(512) void fused_kernel(
    const float* __restrict__ x, const uint32_t* __restrict__ recA,
    const float* __restrict__ recB, const int* __restrict__ start,
    const float* __restrict__ wt, const float* __restrict__ conv_b,
    const float* __restrict__ gn_w, const float* __restrict__ gn_b,
    float* __restrict__ out) {
    __shared__ __align__(16) float tile[PP][CIN];   // 96 KiB

    int n = blockIdx.x;
    int tid = threadIdx.x;

    // zero tile
    float4* t4 = (float4*)&tile[0][0];
#pragma unroll
    for (int j = 0; j < 12; j++) t4[tid + j * 512] = float4{0.f, 0.f, 0.f, 0.f};
    __syncthreads();

    // scatter this bucket's records into the tile
    int b0 = start[n], b1 = start[n + 1];
    {
        int cq = tid & 31;       // channel quad: channels 4*cq..4*cq+3
        int sub = tid >> 5;      // 16 records in flight per iteration
        for (int it = b0; it < b1; it += 16) {
            int idx = it + sub;
            if (idx < b1) {
                uint32_t ra = recA[idx];
                float dl = recB[idx];
                int src = (int)(ra & 0x3FFFFu);
                int p = (int)(ra >> 18);
                float4 xv = ((const float4*)(x + (size_t)src * CIN))[cq];
                float* trow = &tile[p][cq * 4];
                atomicAdd(trow + 0, xv.x * dl);
                atomicAdd(trow + 1, xv.y * dl);
                atomicAdd(trow + 2, xv.z * dl);
                atomicAdd(trow + 3, xv.w * dl);
            }
        }
    }
    __syncthreads();

    // grouped circular conv: thread = (o, q); q covers c'_local {2q, 2q+1}
    int o = tid & 127;
    int q = tid >> 7;
    int g = o >> 3;
    float acc[12];
#pragma unroll
    for (int t = 0; t < 12; t++) acc[t] = 0.f;

#pragma unroll
    for (int c2 = 0; c2 < 2; c2++) {
        int cl = 2 * q + c2;            // in-channel-within-group / 16lat
        int cg = 8 * g + cl;            // sphere channel
#pragma unroll
        for (int lat = 0; lat < LATN; lat++) {
            float r[12];
#pragma unroll
            for (int j = 0; j < 12; j++) r[j] = tile[lat * LONGN + ((j + 6) % 12)][cg];
            int i = cl * LATN + lat;
            const float* wrow = wt + (size_t)i * LONGN * CMID + o;
#pragma unroll
            for (int k = 0; k < 12; k++) {
                float wv = wrow[k * CMID];
#pragma unroll
                for (int t = 0; t < 12; t++) acc[t] += wv * r[(t + k) % 12];
            }
        }
    }
    __syncthreads();

    // reduce partial sums across q, silu, pool, groupnorm
    float* pbuf = &tile[0][0];          // reuse LDS: 4*12*128 + 128 floats
#pragma unroll
    for (int t = 0; t < 12; t++) pbuf[(q * 12 + t) * 128 + o] = acc[t];
    __syncthreads();

    float* gbuf = pbuf + 4 * 12 * 128;
    float sv = 0.f;
    if (tid < 128) {
        float bias = conv_b[o];
#pragma unroll
        for (int t = 0; t < 12; t++) {
            float z = bias;
#pragma unroll
            for (int qq = 0; qq < 4; qq++) z += pbuf[(qq * 12 + t) * 128 + o];
            sv += z / (1.f + __expf(-z));
        }
        sv *= (1.f / 12.f);
        gbuf[o] = sv;
    }
    __syncthreads();
    if (tid < 128) {
        int gb = o & ~7;
        float mu = 0.f, m2 = 0.f;
#pragma unroll
        for (int j = 0; j < 8; j++) {
            float v = gbuf[gb + j];
            mu += v;
            m2 += v * v;
        }
        mu *= 0.125f;
        float var = m2 * 0.125f - mu * mu;
        var = fmaxf(var, 0.f);
        float inv = rsqrtf(var + EPSV);
        out[(size_t)n * CMID + o] = (sv - mu) * inv * gn_w[o] + gn_b[o];
    }
}

extern "C" void kernel_launch(void* const* d_in, const int* in_sizes, int n_in,
                              void* d_out, int out_size, void* d_ws, size_t ws_size,
                              hipStream_t stream) {
    const float* x = (const float*)d_in[0];
    const int* pidx = (const int*)d_in[2];
    const float* delta = (const float*)d_in[3];
    const int* src_idx = (const int*)d_in[4];
    const float* conv_w = (const float*)d_in[5];
    const float* conv_b = (const float*)d_in[6];
    const float* gn_w = (const float*)d_in[7];
    const float* gn_b = (const float*)d_in[8];
    float* out = (float*)d_out;

    int E = in_sizes[0] / CIN;          // 200000
    int N = out_size / CMID;            // 4096

    char* ws = (char*)d_ws;
    size_t off = 0;
    auto alloc = [&](size_t bytes) {
        size_t cur = off;
        off = (off + bytes + 255) & ~(size_t)255;
        return cur;
    };
    int* cur = (int*)(ws + alloc((size_t)N * 4));
    int* start = (int*)(ws + alloc((size_t)(N + 1) * 4));
    uint32_t* recA = (uint32_t*)(ws + alloc((size_t)4 * E * 4));
    float* recB = (float*)(ws + alloc((size_t)4 * E * 4));
    float* wt = (float*)(ws + alloc((size_t)CMID * CIN * LONGN * 4));

    hipMemsetAsync(cur, 0, (size_t)N * 4, stream);

    int gE = (E + 255) / 256;
    count_kernel<<<gE, 256, 0, stream>>>(pidx, cur, E);
    scan_kernel<<<1, 1024, 0, stream>>>(cur, start, cur, N);
    record_kernel<<<gE, 256, 0, stream>>>(pidx, src_idx, delta, cur, recA, recB, E);
    int totW = CMID * CIN * LONGN;
    wt_kernel<<<(totW + 255) / 256, 256, 0, stream>>>(conv_w, wt, totW);
    fused_kernel<<<N, 512, 0, stream>>>(x, recA, recB, start, wt, conv_b, gn_w, gn_b, out);
}

// Round 2
// 732.902 us; speedup vs baseline: 1.6787x; 1.6787x over previous
//
#include <hip/hip_runtime.h>
#include <hip/hip_bf16.h>
#include <cstdint>

#define LATN 16
#define LONGN 12
#define PP 192          // LAT*LONG positions per n
#define CIN 128
#define CMID 128
#define EPSV 1e-5f
#define SPLIT 4         // blocks per n (channel split)
#define CHB 32          // channels per block
#define TSTRIDE 33      // padded LDS tile row stride (floats)

// ---------------- counting sort of scatter records by destination n ----------------

__global__ void count_kernel(const int* __restrict__ pidx, int* __restrict__ counts, int E) {
    int e = blockIdx.x * 256 + threadIdx.x;
    if (e >= E) return;
#pragma unroll
    for (int i = 0; i < 4; i++) {
        int v = pidx[i * E + e];
        int n = v / PP;
        atomicAdd(&counts[n], 1);
    }
}

// single block, 1024 threads, N <= 4096. counts may alias cur.
__global__ void scan_kernel(const int* __restrict__ counts, int* __restrict__ start,
                            int* __restrict__ cur, int N) {
    __shared__ int sdata[1024];
    int tid = threadIdx.x;
    int c[4];
    int s = 0;
#pragma unroll
    for (int j = 0; j < 4; j++) {
        int idx = tid * 4 + j;
        c[j] = (idx < N) ? counts[idx] : 0;
        s += c[j];
    }
    sdata[tid] = s;
    __syncthreads();
    for (int off = 1; off < 1024; off <<= 1) {
        int t = (tid >= off) ? sdata[tid - off] : 0;
        __syncthreads();
        sdata[tid] += t;
        __syncthreads();
    }
    int excl = sdata[tid] - s;
#pragma unroll
    for (int j = 0; j < 4; j++) {
        int idx = tid * 4 + j;
        if (idx < N) { start[idx] = excl; cur[idx] = excl; }
        excl += c[j];
    }
    if (tid == 1023) start[N] = sdata[1023];
}

// emit bucketed records: rec.x = src | (p<<18), rec.y = delta bits
__global__ void record_kernel(const int* __restrict__ pidx, const int* __restrict__ src_idx,
                              const float* __restrict__ delta, int* __restrict__ cur,
                              uint2* __restrict__ rec, int E) {
    int e = blockIdx.x * 256 + threadIdx.x;
    if (e >= E) return;
    int src = src_idx[e];
#pragma unroll
    for (int i = 0; i < 4; i++) {
        int v = pidx[i * E + e];
        int n = v / PP;
        int p = v - n * PP;
        int pos = atomicAdd(&cur[n], 1);
        rec[pos] = make_uint2((uint32_t)src | ((uint32_t)p << 18),
                              __float_as_uint(delta[i * E + e]));
    }
}

// transpose conv weights [o][i][k] -> [i][k][o] for lane-coalesced loads
__global__ void wt_kernel(const float* __restrict__ w, float* __restrict__ wt, int total) {
    int id = blockIdx.x * 256 + threadIdx.x;
    if (id >= total) return;
    int o = id / (CIN * LONGN);
    int rem = id - o * (CIN * LONGN);
    int i = rem / LONGN;
    int k = rem - i * LONGN;
    wt[(i * LONGN + k) * CMID + o] = w[id];
}

// ---------------- fused: scatter->LDS tile, conv, silu, pool, groupnorm ----------------
// One block handles 32 channels (= 4 GroupNorm groups) of one n.

__global__ __launch_bounds__(256, 6) void fused_kernel(
    const float* __restrict__ x, const uint2* __restrict__ rec,
    const int* __restrict__ start, const float* __restrict__ wt,
    const float* __restrict__ conv_b, const float* __restrict__ gn_w,
    const float* __restrict__ gn_b, float* __restrict__ out) {
    __shared__ float tile[PP * TSTRIDE];    // 25344 B

    int bid = blockIdx.x;
    int n = bid >> 2;
    int b = bid & 3;
    int tid = threadIdx.x;

    // zero tile
    for (int i = tid; i < PP * TSTRIDE; i += 256) tile[i] = 0.f;
    __syncthreads();

    // scatter this bucket's records into the tile (32 records in flight)
    int b0 = start[n], b1 = start[n + 1];
    {
        int il = tid & 7;                   // lane within record: 4 channels each
        int slot = tid >> 3;                // 0..31
        int cbase = b * CHB + il * 4;       // global channel of this lane's float4
        for (int it = b0 + slot; it < b1; it += 32) {
            uint2 rv = rec[it];
            float dl = __uint_as_float(rv.y);
            int src = (int)(rv.x & 0x3FFFFu);
            int p = (int)(rv.x >> 18);
            float4 xv = *(const float4*)(x + (size_t)src * CIN + cbase);
            float* trow = tile + p * TSTRIDE + il * 4;
            atomicAdd(trow + 0, xv.x * dl);
            atomicAdd(trow + 1, xv.y * dl);
            atomicAdd(trow + 2, xv.z * dl);
            atomicAdd(trow + 3, xv.w * dl);
        }
    }
    __syncthreads();

    // grouped circular conv: thread = (q, o_local); q = sphere-channel-within-group
    int o_local = tid & 31;
    int q = tid >> 5;                       // 0..7
    int g_local = o_local >> 3;             // 0..3
    int o = b * CHB + o_local;              // global out channel
    int ch_local = g_local * 8 + q;         // tile channel (within block)

    float acc[12];
#pragma unroll
    for (int t = 0; t < 12; t++) acc[t] = 0.f;

#pragma unroll
    for (int lat = 0; lat < LATN; lat++) {
        float r[12];
#pragma unroll
        for (int j = 0; j < 12; j++)
            r[j] = tile[(lat * LONGN + ((j + 6) % 12)) * TSTRIDE + ch_local];
        int i = q * LATN + lat;             // conv in-channel within group
        const float* wrow = wt + (size_t)(i * LONGN) * CMID + o;
#pragma unroll
        for (int k = 0; k < 12; k++) {
            float wv = wrow[k * CMID];
#pragma unroll
            for (int t = 0; t < 12; t++) acc[t] += wv * r[(t + k) % 12];
        }
    }
    __syncthreads();

    // reduce partials across q, silu, pool, groupnorm
    float* pbuf = tile;                     // 8*12*32 = 3072 floats
#pragma unroll
    for (int t = 0; t < 12; t++) pbuf[(q * 12 + t) * 32 + o_local] = acc[t];
    __syncthreads();

    float* gbuf = tile + 8 * 12 * 32;       // 32 floats
    float sv = 0.f;
    if (tid < 32) {
        float bias = conv_b[b * CHB + tid];
#pragma unroll
        for (int t = 0; t < 12; t++) {
            float z = bias;
#pragma unroll
            for (int qq = 0; qq < 8; qq++) z += pbuf[(qq * 12 + t) * 32 + tid];
            sv += z / (1.f + __expf(-z));
        }
        sv *= (1.f / 12.f);
        gbuf[tid] = sv;
    }
    __syncthreads();
    if (tid < 32) {
        int gb = tid & ~7;
        float mu = 0.f, m2 = 0.f;
#pragma unroll
        for (int j = 0; j < 8; j++) {
            float v = gbuf[gb + j];
            mu += v;
            m2 += v * v;
        }
        mu *= 0.125f;
        float var = m2 * 0.125f - mu * mu;
        var = fmaxf(var, 0.f);
        float inv = rsqrtf(var + EPSV);
        int oc = b * CHB + tid;
        out[(size_t)n * CMID + oc] = (sv - mu) * inv * gn_w[oc] + gn_b[oc];
    }
}

extern "C" void kernel_launch(void* const* d_in, const int* in_sizes, int n_in,
                              void* d_out, int out_size, void* d_ws, size_t ws_size,
                              hipStream_t stream) {
    const float* x = (const float*)d_in[0];
    const int* pidx = (const int*)d_in[2];
    const float* delta = (const float*)d_in[3];
    const int* src_idx = (const int*)d_in[4];
    const float* conv_w = (const float*)d_in[5];
    const float* conv_b = (const float*)d_in[6];
    const float* gn_w = (const float*)d_in[7];
    const float* gn_b = (const float*)d_in[8];
    float* out = (float*)d_out;

    int E = in_sizes[0] / CIN;          // 200000
    int N = out_size / CMID;            // 4096

    char* ws = (char*)d_ws;
    size_t off = 0;
    auto alloc = [&](size_t bytes) {
        size_t cur = off;
        off = (off + bytes + 255) & ~(size_t)255;
        return cur;
    };
    int* cur = (int*)(ws + alloc((size_t)N * 4));
    int* start = (int*)(ws + alloc((size_t)(N + 1) * 4));
    uint2* rec = (uint2*)(ws + alloc((size_t)4 * E * 8));
    float* wt = (float*)(ws + alloc((size_t)CMID * CIN * LONGN * 4));

    hipMemsetAsync(cur, 0, (size_t)N * 4, stream);

    int gE = (E + 255) / 256;
    count_kernel<<<gE, 256, 0, stream>>>(pidx, cur, E);
    scan_kernel<<<1, 1024, 0, stream>>>(cur, start, cur, N);
    record_kernel<<<gE, 256, 0, stream>>>(pidx, src_idx, delta, cur, rec, E);
    int totW = CMID * CIN * LONGN;
    wt_kernel<<<(totW + 255) / 256, 256, 0, stream>>>(conv_w, wt, totW);
    fused_kernel<<<N * SPLIT, 256, 0, stream>>>(x, rec, start, wt, conv_b, gn_w, gn_b, out);
}